// Round 1
// baseline (664.147 us; speedup 1.0000x reference)
//
#include <hip/hip_runtime.h>
#include <hip/hip_bf16.h>

typedef unsigned short u16;
typedef __bf16 bf16x8 __attribute__((ext_vector_type(8)));
typedef float f32x4 __attribute__((ext_vector_type(4)));

#define N_TOK 32768
#define DD 512
#define FF 2048
#define EE 8

// ctl layout (ints): [0..7] cnt, [8..15] cursor, [16..24] offs, [25] ntiles,
// [32..303] tile_expert, [304..575] tile_index
#define CTL_CNT 0
#define CTL_CUR 8
#define CTL_OFF 16
#define CTL_NT 25
#define CTL_TE 32
#define CTL_TI 304

__device__ inline u16 f2bu(float f) {
  unsigned u = __builtin_bit_cast(unsigned, f);
  unsigned r = (u + 0x7fffu + ((u >> 16) & 1u)) >> 16;  // RNE
  return (u16)r;
}

__device__ inline f32x4 mfma16(bf16x8 a, bf16x8 b, f32x4 c) {
  return __builtin_amdgcn_mfma_f32_16x16x32_bf16(a, b, c, 0, 0, 0);
}

__device__ inline void gload_lds16(const void* g, void* l) {
  __builtin_amdgcn_global_load_lds(
      (const __attribute__((address_space(1))) void*)g,
      (__attribute__((address_space(3))) void*)l, 16, 0, 0);
}

// Stage a 128-row x 32-col bf16 tile (row stride ld elems) into LDS linearly.
// 256 threads x 2 insts x 16B = 8192 B. LDS dest = wave-uniform base + lane*16.
__device__ inline void stage128x32(u16* lds, const u16* g, int ld) {
  const int t = threadIdx.x;
#pragma unroll
  for (int s = 0; s < 2; ++s) {
    const int e = s * 2048 + t * 8;   // elem offset in tile
    const int row = e >> 5;           // /32
    const int kin = e & 31;           // %32
    gload_lds16(g + (size_t)row * ld + kin, lds + e);
  }
}

// ---------------- gating: one wave per token ----------------
__global__ void gate_k(const float* __restrict__ x, const float* __restrict__ gw,
                       const float* __restrict__ gb, int* __restrict__ eid,
                       float* __restrict__ wgt) {
  __shared__ float gws[DD * EE];
  for (int i = threadIdx.x; i < DD * EE; i += 256) gws[i] = gw[i];
  __syncthreads();
  const int tok = (int)((blockIdx.x * 256 + threadIdx.x) >> 6);
  const int lane = threadIdx.x & 63;
  const float* xr = x + (size_t)tok * DD;
  float a[EE];
#pragma unroll
  for (int e = 0; e < EE; ++e) a[e] = 0.f;
#pragma unroll
  for (int i = 0; i < 8; ++i) {
    const int d = lane + i * 64;
    const float xv = xr[d];
#pragma unroll
    for (int e = 0; e < EE; ++e) a[e] += xv * gws[d * EE + e];
  }
#pragma unroll
  for (int e = 0; e < EE; ++e) {
#pragma unroll
    for (int off = 32; off > 0; off >>= 1) a[e] += __shfl_xor(a[e], off);
  }
  if (lane == 0) {
    float m = -1e30f; int bi = 0;
#pragma unroll
    for (int e = 0; e < EE; ++e) {
      const float l2 = a[e] + gb[e];
      a[e] = l2;
      if (l2 > m) { m = l2; bi = e; }   // strict > : first max, matches argmax
    }
    float s = 0.f;
#pragma unroll
    for (int e = 0; e < EE; ++e) s += expf(a[e] - m);
    eid[tok] = bi;
    wgt[tok] = 1.f / s;                 // softmax prob at argmax
  }
}

// ---------------- counting sort ----------------
__global__ void count_k(const int* __restrict__ eid, int* __restrict__ ctl) {
  __shared__ int h[EE];
  if (threadIdx.x < EE) h[threadIdx.x] = 0;
  __syncthreads();
  atomicAdd(&h[eid[blockIdx.x * 256 + threadIdx.x]], 1);
  __syncthreads();
  if (threadIdx.x < EE) atomicAdd(&ctl[CTL_CNT + threadIdx.x], h[threadIdx.x]);
}

__global__ void scan_k(int* __restrict__ ctl, float* __restrict__ aux) {
  int o = 0, nt = 0;
  for (int e = 0; e < EE; ++e) {
    ctl[CTL_OFF + e] = o;
    ctl[CTL_CUR + e] = o;
    const int c = ctl[CTL_CNT + e];
    const int t = (c + 127) >> 7;
    for (int i = 0; i < t; ++i) { ctl[CTL_TE + nt] = e; ctl[CTL_TI + nt] = i; ++nt; }
    o += c;
  }
  ctl[CTL_OFF + 8] = o;
  ctl[CTL_NT] = nt;
  *aux = 0.f;  // aux_loss output
}

__global__ void pos_k(const int* __restrict__ eid, const float* __restrict__ wgt,
                      int* __restrict__ ctl, int* __restrict__ sorted,
                      float* __restrict__ wgt_s) {
  __shared__ int h[EE], base[EE];
  const int t = blockIdx.x * 256 + threadIdx.x;
  if (threadIdx.x < EE) h[threadIdx.x] = 0;
  __syncthreads();
  const int e = eid[t];
  const int r = atomicAdd(&h[e], 1);
  __syncthreads();
  if (threadIdx.x < EE)
    base[threadIdx.x] = atomicAdd(&ctl[CTL_CUR + threadIdx.x], h[threadIdx.x]);
  __syncthreads();
  const int p = base[e] + r;
  sorted[p] = t;
  wgt_s[p] = wgt[t];
}

// gather x rows into sorted bf16 layout; one wave per destination row
__global__ void gather_k(const float* __restrict__ x, const int* __restrict__ sorted,
                         u16* __restrict__ Xg) {
  const int p = (int)((blockIdx.x * 256 + threadIdx.x) >> 6);
  const int lane = threadIdx.x & 63;
  const int t = sorted[p];
  const float* src = x + (size_t)t * DD + lane * 8;
  const float4 v0 = *(const float4*)(src);
  const float4 v1 = *(const float4*)(src + 4);
  union { u16 u[8]; uint4 v; } o;
  o.u[0] = f2bu(v0.x); o.u[1] = f2bu(v0.y); o.u[2] = f2bu(v0.z); o.u[3] = f2bu(v0.w);
  o.u[4] = f2bu(v1.x); o.u[5] = f2bu(v1.y); o.u[6] = f2bu(v1.z); o.u[7] = f2bu(v1.w);
  *reinterpret_cast<uint4*>(Xg + (size_t)p * DD + lane * 8) = o.v;
}

// out[e][c][r] = bf16(in[e][r][c]); 64x64 tiles via LDS (+2 pad: conflict-free)
__global__ void transp_k(const float* __restrict__ in, u16* __restrict__ out,
                         int R, int C) {
  __shared__ u16 tile[64][66];
  const int e = blockIdx.z;
  const int c0 = blockIdx.x * 64, r0 = blockIdx.y * 64;
  const float* ip = in + (size_t)e * R * C;
  u16* op = out + (size_t)e * R * C;
  const int tx = threadIdx.x & 63, ty = threadIdx.x >> 6;
#pragma unroll
  for (int k = 0; k < 16; ++k) {
    const int r = ty * 16 + k;
    tile[r][tx] = f2bu(ip[(size_t)(r0 + r) * C + c0 + tx]);
  }
  __syncthreads();
#pragma unroll
  for (int k = 0; k < 16; ++k) {
    const int c = ty * 16 + k;
    op[(size_t)(c0 + c) * R + r0 + tx] = tile[tx][c];
  }
}

// ---------------- GEMM1: H = gelu(Xg@W1+b1)*(Xg@W2+b2), K=512 ----------------
// 128x128 tile, 4 waves (2x2), each wave 64x64 = 4x4 frags of 16x16x32.
__global__ __launch_bounds__(256, 2) void gemm1_k(
    const u16* __restrict__ Xg, const u16* __restrict__ W1t,
    const u16* __restrict__ W2t, const float* __restrict__ b1,
    const float* __restrict__ b2, u16* __restrict__ Hbuf,
    const int* __restrict__ ctl) {
  const int bx = blockIdx.x;
  if (bx >= ctl[CTL_NT]) return;
  const int e = ctl[CTL_TE + bx];
  const int ti = ctl[CTL_TI + bx];
  const int cnt = ctl[CTL_CNT + e];
  const int row0 = ctl[CTL_OFF + e] + ti * 128;
  const int rows = min(128, cnt - ti * 128);
  const int n0 = blockIdx.y * 128;

  __shared__ u16 As[2][4096];
  __shared__ u16 B1s[2][4096];
  __shared__ u16 B2s[2][4096];

  const u16* Ab = Xg + (size_t)row0 * DD;
  const u16* B1b = W1t + ((size_t)e * FF + n0) * DD;
  const u16* B2b = W2t + ((size_t)e * FF + n0) * DD;

  const f32x4 z = {0.f, 0.f, 0.f, 0.f};
  f32x4 acc1[4][4], acc2[4][4];
#pragma unroll
  for (int i = 0; i < 4; ++i)
#pragma unroll
    for (int j = 0; j < 4; ++j) { acc1[i][j] = z; acc2[i][j] = z; }

  stage128x32(As[0], Ab, DD);
  stage128x32(B1s[0], B1b, DD);
  stage128x32(B2s[0], B2b, DD);
  asm volatile("s_waitcnt vmcnt(0)" ::: "memory");
  __syncthreads();

  const int lane = threadIdx.x & 63;
  const int w = threadIdx.x >> 6;
  const int wr = w >> 1, wc = w & 1;
  const int ro = (lane & 15) * 32 + (lane >> 4) * 8;

  int cur = 0;
  for (int kt = 0; kt < 16; ++kt) {
    if (kt < 15) {
      stage128x32(As[cur ^ 1], Ab + (kt + 1) * 32, DD);
      stage128x32(B1s[cur ^ 1], B1b + (kt + 1) * 32, DD);
      stage128x32(B2s[cur ^ 1], B2b + (kt + 1) * 32, DD);
    }
    bf16x8 af[4], bf1[4], bf2[4];
#pragma unroll
    for (int mi = 0; mi < 4; ++mi)
      af[mi] = *(const bf16x8*)&As[cur][(wr * 64 + mi * 16) * 32 + ro];
#pragma unroll
    for (int ni = 0; ni < 4; ++ni) {
      bf1[ni] = *(const bf16x8*)&B1s[cur][(wc * 64 + ni * 16) * 32 + ro];
      bf2[ni] = *(const bf16x8*)&B2s[cur][(wc * 64 + ni * 16) * 32 + ro];
    }
#pragma unroll
    for (int mi = 0; mi < 4; ++mi)
#pragma unroll
      for (int ni = 0; ni < 4; ++ni) {
        acc1[mi][ni] = mfma16(af[mi], bf1[ni], acc1[mi][ni]);
        acc2[mi][ni] = mfma16(af[mi], bf2[ni], acc2[mi][ni]);
      }
    asm volatile("s_waitcnt vmcnt(0)" ::: "memory");
    __syncthreads();
    cur ^= 1;
  }

#pragma unroll
  for (int mi = 0; mi < 4; ++mi) {
#pragma unroll
    for (int ni = 0; ni < 4; ++ni) {
      const int c = wc * 64 + ni * 16 + (lane & 15);
      const float bb1 = b1[(size_t)e * FF + n0 + c];
      const float bb2 = b2[(size_t)e * FF + n0 + c];
#pragma unroll
      for (int j = 0; j < 4; ++j) {
        const int r = wr * 64 + mi * 16 + (lane >> 4) * 4 + j;
        if (r < rows) {
          const float v1 = acc1[mi][ni][j] + bb1;
          const float v2 = acc2[mi][ni][j] + bb2;
          const float h = 0.5f * v1 * (1.f + erff(v1 * 0.70710678118f)) * v2;
          Hbuf[(size_t)(row0 + r) * FF + n0 + c] = f2bu(h);
        }
      }
    }
  }
}

// ---------------- GEMM2: out[tok] = wgt * (H@W3 + b3), K=2048 ----------------
__global__ __launch_bounds__(256, 2) void gemm2_k(
    const u16* __restrict__ Hbuf, const u16* __restrict__ W3t,
    const float* __restrict__ b3, const int* __restrict__ sorted,
    const float* __restrict__ wgt_s, float* __restrict__ out,
    const int* __restrict__ ctl) {
  const int bx = blockIdx.x;
  if (bx >= ctl[CTL_NT]) return;
  const int e = ctl[CTL_TE + bx];
  const int ti = ctl[CTL_TI + bx];
  const int cnt = ctl[CTL_CNT + e];
  const int row0 = ctl[CTL_OFF + e] + ti * 128;
  const int rows = min(128, cnt - ti * 128);
  const int n0 = blockIdx.y * 128;

  __shared__ u16 As[2][4096];
  __shared__ u16 Bs[2][4096];
  const u16* Ab = Hbuf + (size_t)row0 * FF;
  const u16* Bb = W3t + ((size_t)e * DD + n0) * FF;

  const f32x4 z = {0.f, 0.f, 0.f, 0.f};
  f32x4 acc[4][4];
#pragma unroll
  for (int i = 0; i < 4; ++i)
#pragma unroll
    for (int j = 0; j < 4; ++j) acc[i][j] = z;

  stage128x32(As[0], Ab, FF);
  stage128x32(Bs[0], Bb, FF);
  asm volatile("s_waitcnt vmcnt(0)" ::: "memory");
  __syncthreads();

  const int lane = threadIdx.x & 63;
  const int w = threadIdx.x >> 6;
  const int wr = w >> 1, wc = w & 1;
  const int ro = (lane & 15) * 32 + (lane >> 4) * 8;

  int cur = 0;
  for (int kt = 0; kt < 64; ++kt) {
    if (kt < 63) {
      stage128x32(As[cur ^ 1], Ab + (kt + 1) * 32, FF);
      stage128x32(Bs[cur ^ 1], Bb + (kt + 1) * 32, FF);
    }
    bf16x8 af[4], bf[4];
#pragma unroll
    for (int mi = 0; mi < 4; ++mi)
      af[mi] = *(const bf16x8*)&As[cur][(wr * 64 + mi * 16) * 32 + ro];
#pragma unroll
    for (int ni = 0; ni < 4; ++ni)
      bf[ni] = *(const bf16x8*)&Bs[cur][(wc * 64 + ni * 16) * 32 + ro];
#pragma unroll
    for (int mi = 0; mi < 4; ++mi)
#pragma unroll
      for (int ni = 0; ni < 4; ++ni)
        acc[mi][ni] = mfma16(af[mi], bf[ni], acc[mi][ni]);
    asm volatile("s_waitcnt vmcnt(0)" ::: "memory");
    __syncthreads();
    cur ^= 1;
  }

#pragma unroll
  for (int mi = 0; mi < 4; ++mi) {
#pragma unroll
    for (int ni = 0; ni < 4; ++ni) {
      const int c = wc * 64 + ni * 16 + (lane & 15);
      const float bb3 = b3[(size_t)e * DD + n0 + c];
#pragma unroll
      for (int j = 0; j < 4; ++j) {
        const int r = wr * 64 + mi * 16 + (lane >> 4) * 4 + j;
        if (r < rows) {
          const int p = row0 + r;
          const int tok = sorted[p];
          out[(size_t)tok * DD + n0 + c] = wgt_s[p] * (acc[mi][ni][j] + bb3);
        }
      }
    }
  }
}

extern "C" void kernel_launch(void* const* d_in, const int* in_sizes, int n_in,
                              void* d_out, int out_size, void* d_ws, size_t ws_size,
                              hipStream_t stream) {
  const float* x  = (const float*)d_in[0];
  const float* gw = (const float*)d_in[1];
  const float* gb = (const float*)d_in[2];
  const float* w1 = (const float*)d_in[3];
  const float* b1 = (const float*)d_in[4];
  const float* w2 = (const float*)d_in[5];
  const float* b2 = (const float*)d_in[6];
  const float* w3 = (const float*)d_in[7];
  const float* b3 = (const float*)d_in[8];
  float* out = (float*)d_out;

  char* base = (char*)d_ws;
  size_t off = 0;
  auto take = [&](size_t bytes) {
    char* r = base + off;
    off += (bytes + 255) & ~(size_t)255;
    return r;
  };
  int*   ctl    = (int*)take(4096);
  int*   eid    = (int*)take((size_t)N_TOK * 4);
  float* wgt    = (float*)take((size_t)N_TOK * 4);
  int*   sorted = (int*)take((size_t)(N_TOK + 128) * 4);
  float* wgt_s  = (float*)take((size_t)(N_TOK + 128) * 4);
  u16*   Xg     = (u16*)take((size_t)(N_TOK + 128) * DD * 2);
  u16*   W1t    = (u16*)take((size_t)EE * FF * DD * 2);
  u16*   W2t    = (u16*)take((size_t)EE * FF * DD * 2);
  u16*   W3t    = (u16*)take((size_t)EE * DD * FF * 2);
  u16*   Hbuf   = (u16*)take((size_t)(N_TOK + 128) * FF * 2);

  hipMemsetAsync(ctl, 0, 64, stream);  // cnt+cursor zeroed (ws is re-poisoned)

  gate_k<<<8192, 256, 0, stream>>>(x, gw, gb, eid, wgt);
  count_k<<<128, 256, 0, stream>>>(eid, ctl);
  scan_k<<<1, 1, 0, stream>>>(ctl, out + (size_t)N_TOK * DD);
  pos_k<<<128, 256, 0, stream>>>(eid, wgt, ctl, sorted, wgt_s);
  gather_k<<<8192, 256, 0, stream>>>(x, sorted, Xg);

  transp_k<<<dim3(32, 8, EE), 256, 0, stream>>>(w1, W1t, 512, 2048);
  transp_k<<<dim3(32, 8, EE), 256, 0, stream>>>(w2, W2t, 512, 2048);
  transp_k<<<dim3(8, 32, EE), 256, 0, stream>>>(w3, W3t, 2048, 512);

  gemm1_k<<<dim3(264, 16), 256, 0, stream>>>(Xg, W1t, W2t, b1, b2, Hbuf, ctl);
  gemm2_k<<<dim3(264, 4), 256, 0, stream>>>(Hbuf, W3t, b3, sorted, wgt_s, out, ctl);
}

// Round 4
// 619.988 us; speedup vs baseline: 1.0712x; 1.0712x over previous
//
#include <hip/hip_runtime.h>
#include <hip/hip_bf16.h>

typedef unsigned short u16;
typedef __bf16 bf16x8 __attribute__((ext_vector_type(8)));
typedef float f32x4 __attribute__((ext_vector_type(4)));

#define N_TOK 32768
#define DD 512
#define FF 2048
#define EE 8

// ctl layout (ints): [0..7] cnt, [8..15] cursor, [16..24] offs, [25] ntiles,
// [32..303] tile_expert, [304..575] tile_index
#define CTL_CNT 0
#define CTL_CUR 8
#define CTL_OFF 16
#define CTL_NT 25
#define CTL_TE 32
#define CTL_TI 304

__device__ inline u16 f2bu(float f) {
  unsigned u = __builtin_bit_cast(unsigned, f);
  unsigned r = (u + 0x7fffu + ((u >> 16) & 1u)) >> 16;  // RNE
  return (u16)r;
}

__device__ inline f32x4 mfma16(bf16x8 a, bf16x8 b, f32x4 c) {
  return __builtin_amdgcn_mfma_f32_16x16x32_bf16(a, b, c, 0, 0, 0);
}

__device__ inline void gload_lds16(const void* g, void* l) {
  __builtin_amdgcn_global_load_lds(
      (const __attribute__((address_space(1))) void*)g,
      (__attribute__((address_space(3))) void*)l, 16, 0, 0);
}

// LDS tile: 128 rows x 32 cols bf16, 16B granules. Logical granule (r,g)
// lives at physical granule G' = (r*4+g) ^ (r&7)  [XOR-swizzle, bank-
// conflict-free for the MFMA fragment read pattern]. global_load_lds writes
// linearly, so the WRITER inverts the swizzle on the global source address.
// Inverse of G' -> (r,g):  r = ((G'>>3)<<1) | (((G'>>2)^(G'>>4))&1),
//                          g = (G'&3) ^ (r&3).

// ---------------- gating + bf16 convert: one wave per token ----------------
__global__ void gate_k(const float* __restrict__ x, const float* __restrict__ gw,
                       const float* __restrict__ gb, int* __restrict__ eid,
                       float* __restrict__ wgt, u16* __restrict__ Xb) {
  __shared__ float gws[DD * 9];  // padded [D][9]: 9 coprime 32 -> no conflicts
  for (int i = threadIdx.x; i < DD * EE; i += 256)
    gws[(i >> 3) * 9 + (i & 7)] = gw[i];
  __syncthreads();
  const int tok = (int)((blockIdx.x * 256 + threadIdx.x) >> 6);
  const int lane = threadIdx.x & 63;
  const float* xr = x + (size_t)tok * DD;

  // bf16 copy of this token's row (contiguous per lane)
  const float4 v0 = *(const float4*)(xr + lane * 8);
  const float4 v1 = *(const float4*)(xr + lane * 8 + 4);
  union { u16 u[8]; uint4 v; } o;
  o.u[0] = f2bu(v0.x); o.u[1] = f2bu(v0.y); o.u[2] = f2bu(v0.z); o.u[3] = f2bu(v0.w);
  o.u[4] = f2bu(v1.x); o.u[5] = f2bu(v1.y); o.u[6] = f2bu(v1.z); o.u[7] = f2bu(v1.w);
  *reinterpret_cast<uint4*>(Xb + (size_t)tok * DD + lane * 8) = o.v;

  float a[EE];
#pragma unroll
  for (int e = 0; e < EE; ++e) a[e] = 0.f;
#pragma unroll
  for (int i = 0; i < 8; ++i) {
    const int d = lane + i * 64;
    const float xv = xr[d];
#pragma unroll
    for (int e = 0; e < EE; ++e) a[e] += xv * gws[d * 9 + e];
  }
#pragma unroll
  for (int e = 0; e < EE; ++e) {
#pragma unroll
    for (int off = 32; off > 0; off >>= 1) a[e] += __shfl_xor(a[e], off);
  }
  if (lane == 0) {
    float m = -1e30f; int bi = 0;
#pragma unroll
    for (int e = 0; e < EE; ++e) {
      const float l2 = a[e] + gb[e];
      a[e] = l2;
      if (l2 > m) { m = l2; bi = e; }   // strict > : first max, matches argmax
    }
    float s = 0.f;
#pragma unroll
    for (int e = 0; e < EE; ++e) s += expf(a[e] - m);
    eid[tok] = bi;
    wgt[tok] = 1.f / s;                 // softmax prob at argmax
  }
}

// ---------------- counting sort ----------------
__global__ void count_k(const int* __restrict__ eid, int* __restrict__ ctl) {
  __shared__ int h[EE];
  if (threadIdx.x < EE) h[threadIdx.x] = 0;
  __syncthreads();
  atomicAdd(&h[eid[blockIdx.x * 256 + threadIdx.x]], 1);
  __syncthreads();
  if (threadIdx.x < EE) atomicAdd(&ctl[CTL_CNT + threadIdx.x], h[threadIdx.x]);
}

__global__ void scan_k(int* __restrict__ ctl, float* __restrict__ aux) {
  __shared__ int tstart[EE + 1];
  if (threadIdx.x == 0) {
    int o = 0, nt = 0;
    for (int e = 0; e < EE; ++e) {
      ctl[CTL_OFF + e] = o;
      ctl[CTL_CUR + e] = o;
      tstart[e] = nt;
      const int c = ctl[CTL_CNT + e];
      nt += (c + 127) >> 7;
      o += c;
    }
    tstart[EE] = nt;
    ctl[CTL_OFF + 8] = o;
    ctl[CTL_NT] = nt;
    *aux = 0.f;  // aux_loss output
  }
  __syncthreads();
  const int nt = tstart[EE];
  for (int i = threadIdx.x; i < nt; i += 256) {
    int e = 0;
    while (tstart[e + 1] <= i) ++e;
    ctl[CTL_TE + i] = e;
    ctl[CTL_TI + i] = i - tstart[e];
  }
}

__global__ void pos_k(const int* __restrict__ eid, const float* __restrict__ wgt,
                      int* __restrict__ ctl, int* __restrict__ sorted,
                      float* __restrict__ wgt_s) {
  __shared__ int h[EE], base[EE];
  const int t = blockIdx.x * 256 + threadIdx.x;
  if (threadIdx.x < EE) h[threadIdx.x] = 0;
  __syncthreads();
  const int e = eid[t];
  const int r = atomicAdd(&h[e], 1);
  __syncthreads();
  if (threadIdx.x < EE)
    base[threadIdx.x] = atomicAdd(&ctl[CTL_CUR + threadIdx.x], h[threadIdx.x]);
  __syncthreads();
  const int p = base[e] + r;
  sorted[p] = t;
  wgt_s[p] = wgt[t];
}

// out[e][c][r] = bf16(in[e][r][c]); 64x64 tiles via LDS (+2 pad: conflict-free)
__global__ void transp_k(const float* __restrict__ in, u16* __restrict__ out,
                         int R, int C) {
  __shared__ u16 tile[64][66];
  const int e = blockIdx.z;
  const int c0 = blockIdx.x * 64, r0 = blockIdx.y * 64;
  const float* ip = in + (size_t)e * R * C;
  u16* op = out + (size_t)e * R * C;
  const int tx = threadIdx.x & 63, ty = threadIdx.x >> 6;
#pragma unroll
  for (int k = 0; k < 16; ++k) {
    const int r = ty * 16 + k;
    tile[r][tx] = f2bu(ip[(size_t)(r0 + r) * C + c0 + tx]);
  }
  __syncthreads();
#pragma unroll
  for (int k = 0; k < 16; ++k) {
    const int c = ty * 16 + k;
    op[(size_t)(c0 + c) * R + r0 + tx] = tile[tx][c];
  }
}

// ---------------- GEMM1: H = gelu(Xg@W1+b1)*(Xg@W2+b2), K=512 ----------------
// 128x128 tile, 4 waves (2x2), each wave 64x64 = 4x4 frags of 16x16x32.
// A rows gathered through sorted[] at stage time (per-lane global addr).
__global__ __launch_bounds__(256, 2) void gemm1_k(
    const u16* __restrict__ Xb, const u16* __restrict__ W1t,
    const u16* __restrict__ W2t, const float* __restrict__ b1,
    const float* __restrict__ b2, u16* __restrict__ Hbuf,
    const int* __restrict__ sorted, const int* __restrict__ ctl) {
  const int bx = blockIdx.x;
  if (bx >= ctl[CTL_NT]) return;
  const int e = ctl[CTL_TE + bx];
  const int ti = ctl[CTL_TI + bx];
  const int cnt = ctl[CTL_CNT + e];
  const int row0 = ctl[CTL_OFF + e] + ti * 128;
  const int rows = min(128, cnt - ti * 128);
  const int n0 = blockIdx.y * 128;

  __shared__ u16 As[2][4096];
  __shared__ u16 B1s[2][4096];
  __shared__ u16 B2s[2][4096];

  const u16* B1b = W1t + ((size_t)e * FF + n0) * DD;
  const u16* B2b = W2t + ((size_t)e * FF + n0) * DD;

  // ---- swizzled stage sources (loop-invariant per thread) ----
  const int t = threadIdx.x;
  const u16 *aSrc[2], *b1Src[2], *b2Src[2];
  int dofs[2];
#pragma unroll
  for (int s = 0; s < 2; ++s) {
    const int Gp = s * 256 + t;
    const int r = ((Gp >> 3) << 1) | (((Gp >> 2) ^ (Gp >> 4)) & 1);
    const int g = (Gp & 3) ^ (r & 3);
    dofs[s] = Gp * 8;
    const int idx = min(row0 + r, N_TOK - 1);
    aSrc[s]  = Xb + (size_t)sorted[idx] * DD + g * 8;
    b1Src[s] = B1b + (size_t)r * DD + g * 8;
    b2Src[s] = B2b + (size_t)r * DD + g * 8;
  }
  auto stage_all = [&](int buf, int kc) {
#pragma unroll
    for (int s = 0; s < 2; ++s) gload_lds16(aSrc[s] + kc, &As[buf][dofs[s]]);
#pragma unroll
    for (int s = 0; s < 2; ++s) gload_lds16(b1Src[s] + kc, &B1s[buf][dofs[s]]);
#pragma unroll
    for (int s = 0; s < 2; ++s) gload_lds16(b2Src[s] + kc, &B2s[buf][dofs[s]]);
  };

  const f32x4 z = {0.f, 0.f, 0.f, 0.f};
  f32x4 acc1[4][4], acc2[4][4];
#pragma unroll
  for (int i = 0; i < 4; ++i)
#pragma unroll
    for (int j = 0; j < 4; ++j) { acc1[i][j] = z; acc2[i][j] = z; }

  stage_all(0, 0);
  asm volatile("s_waitcnt vmcnt(0)" ::: "memory");
  __syncthreads();

  // ---- swizzled fragment read offsets ----
  const int lane = threadIdx.x & 63;
  const int w = t >> 6;
  const int wr = w >> 1, wc = w & 1;
  const int l15 = lane & 15, g8 = (lane >> 4) * 8, xv = (lane & 7) << 3;
  int offA[4], offB[4];
#pragma unroll
  for (int i = 0; i < 4; ++i) {
    offA[i] = (((wr * 64 + i * 16 + l15) * 32 + g8) ^ xv);
    offB[i] = (((wc * 64 + i * 16 + l15) * 32 + g8) ^ xv);
  }

  int cur = 0;
  for (int kt = 0; kt < 16; ++kt) {
    if (kt < 15) stage_all(cur ^ 1, (kt + 1) * 32);
    bf16x8 af[4], bf1[4], bf2[4];
#pragma unroll
    for (int mi = 0; mi < 4; ++mi)
      af[mi] = *(const bf16x8*)&As[cur][offA[mi]];
#pragma unroll
    for (int ni = 0; ni < 4; ++ni) {
      bf1[ni] = *(const bf16x8*)&B1s[cur][offB[ni]];
      bf2[ni] = *(const bf16x8*)&B2s[cur][offB[ni]];
    }
#pragma unroll
    for (int mi = 0; mi < 4; ++mi)
#pragma unroll
      for (int ni = 0; ni < 4; ++ni) {
        acc1[mi][ni] = mfma16(af[mi], bf1[ni], acc1[mi][ni]);
        acc2[mi][ni] = mfma16(af[mi], bf2[ni], acc2[mi][ni]);
      }
    asm volatile("s_waitcnt vmcnt(0)" ::: "memory");
    __syncthreads();
    cur ^= 1;
  }

#pragma unroll
  for (int mi = 0; mi < 4; ++mi) {
#pragma unroll
    for (int ni = 0; ni < 4; ++ni) {
      const int c = wc * 64 + ni * 16 + (lane & 15);
      const float bb1 = b1[(size_t)e * FF + n0 + c];
      const float bb2 = b2[(size_t)e * FF + n0 + c];
#pragma unroll
      for (int j = 0; j < 4; ++j) {
        const int r = wr * 64 + mi * 16 + (lane >> 4) * 4 + j;
        if (r < rows) {
          const float v1 = acc1[mi][ni][j] + bb1;
          const float v2 = acc2[mi][ni][j] + bb2;
          const float h = 0.5f * v1 * (1.f + erff(v1 * 0.70710678118f)) * v2;
          Hbuf[(size_t)(row0 + r) * FF + n0 + c] = f2bu(h);
        }
      }
    }
  }
}

// ---------------- GEMM2: out[tok] = wgt * (H@W3 + b3), K=2048 ----------------
__global__ __launch_bounds__(256, 2) void gemm2_k(
    const u16* __restrict__ Hbuf, const u16* __restrict__ W3t,
    const float* __restrict__ b3, const int* __restrict__ sorted,
    const float* __restrict__ wgt_s, float* __restrict__ out,
    const int* __restrict__ ctl) {
  const int bx = blockIdx.x;
  if (bx >= ctl[CTL_NT]) return;
  const int e = ctl[CTL_TE + bx];
  const int ti = ctl[CTL_TI + bx];
  const int cnt = ctl[CTL_CNT + e];
  const int row0 = ctl[CTL_OFF + e] + ti * 128;
  const int rows = min(128, cnt - ti * 128);
  const int n0 = blockIdx.y * 128;

  __shared__ u16 As[2][4096];
  __shared__ u16 Bs[2][4096];
  const u16* Ab = Hbuf + (size_t)row0 * FF;
  const u16* Bb = W3t + ((size_t)e * DD + n0) * FF;

  const int t = threadIdx.x;
  const u16 *aSrc[2], *bSrc[2];
  int dofs[2];
#pragma unroll
  for (int s = 0; s < 2; ++s) {
    const int Gp = s * 256 + t;
    const int r = ((Gp >> 3) << 1) | (((Gp >> 2) ^ (Gp >> 4)) & 1);
    const int g = (Gp & 3) ^ (r & 3);
    dofs[s] = Gp * 8;
    aSrc[s] = Ab + (size_t)r * FF + g * 8;
    bSrc[s] = Bb + (size_t)r * FF + g * 8;
  }
  auto stage_all = [&](int buf, int kc) {
#pragma unroll
    for (int s = 0; s < 2; ++s) gload_lds16(aSrc[s] + kc, &As[buf][dofs[s]]);
#pragma unroll
    for (int s = 0; s < 2; ++s) gload_lds16(bSrc[s] + kc, &Bs[buf][dofs[s]]);
  };

  const f32x4 z = {0.f, 0.f, 0.f, 0.f};
  f32x4 acc[4][4];
#pragma unroll
  for (int i = 0; i < 4; ++i)
#pragma unroll
    for (int j = 0; j < 4; ++j) acc[i][j] = z;

  stage_all(0, 0);
  asm volatile("s_waitcnt vmcnt(0)" ::: "memory");
  __syncthreads();

  const int lane = threadIdx.x & 63;
  const int w = t >> 6;
  const int wr = w >> 1, wc = w & 1;
  const int l15 = lane & 15, g8 = (lane >> 4) * 8, xv = (lane & 7) << 3;
  int offA[4], offB[4];
#pragma unroll
  for (int i = 0; i < 4; ++i) {
    offA[i] = (((wr * 64 + i * 16 + l15) * 32 + g8) ^ xv);
    offB[i] = (((wc * 64 + i * 16 + l15) * 32 + g8) ^ xv);
  }

  int cur = 0;
  for (int kt = 0; kt < 64; ++kt) {
    if (kt < 63) stage_all(cur ^ 1, (kt + 1) * 32);
    bf16x8 af[4], bf[4];
#pragma unroll
    for (int mi = 0; mi < 4; ++mi)
      af[mi] = *(const bf16x8*)&As[cur][offA[mi]];
#pragma unroll
    for (int ni = 0; ni < 4; ++ni)
      bf[ni] = *(const bf16x8*)&Bs[cur][offB[ni]];
#pragma unroll
    for (int mi = 0; mi < 4; ++mi)
#pragma unroll
      for (int ni = 0; ni < 4; ++ni)
        acc[mi][ni] = mfma16(af[mi], bf[ni], acc[mi][ni]);
    asm volatile("s_waitcnt vmcnt(0)" ::: "memory");
    __syncthreads();
    cur ^= 1;
  }

#pragma unroll
  for (int mi = 0; mi < 4; ++mi) {
#pragma unroll
    for (int ni = 0; ni < 4; ++ni) {
      const int c = wc * 64 + ni * 16 + (lane & 15);
      const float bb3 = b3[(size_t)e * DD + n0 + c];
#pragma unroll
      for (int j = 0; j < 4; ++j) {
        const int r = wr * 64 + mi * 16 + (lane >> 4) * 4 + j;
        if (r < rows) {
          const int p = row0 + r;
          const int tok = sorted[p];
          out[(size_t)tok * DD + n0 + c] = wgt_s[p] * (acc[mi][ni][j] + bb3);
        }
      }
    }
  }
}

extern "C" void kernel_launch(void* const* d_in, const int* in_sizes, int n_in,
                              void* d_out, int out_size, void* d_ws, size_t ws_size,
                              hipStream_t stream) {
  const float* x  = (const float*)d_in[0];
  const float* gw = (const float*)d_in[1];
  const float* gb = (const float*)d_in[2];
  const float* w1 = (const float*)d_in[3];
  const float* b1 = (const float*)d_in[4];
  const float* w2 = (const float*)d_in[5];
  const float* b2 = (const float*)d_in[6];
  const float* w3 = (const float*)d_in[7];
  const float* b3 = (const float*)d_in[8];
  float* out = (float*)d_out;

  char* base = (char*)d_ws;
  size_t off = 0;
  auto take = [&](size_t bytes) {
    char* r = base + off;
    off += (bytes + 255) & ~(size_t)255;
    return r;
  };
  int*   ctl    = (int*)take(4096);
  int*   eid    = (int*)take((size_t)N_TOK * 4);
  float* wgt    = (float*)take((size_t)N_TOK * 4);
  int*   sorted = (int*)take((size_t)(N_TOK + 128) * 4);
  float* wgt_s  = (float*)take((size_t)(N_TOK + 128) * 4);
  u16*   Xb     = (u16*)take((size_t)N_TOK * DD * 2);
  u16*   W1t    = (u16*)take((size_t)EE * FF * DD * 2);
  u16*   W2t    = (u16*)take((size_t)EE * FF * DD * 2);
  u16*   W3t    = (u16*)take((size_t)EE * DD * FF * 2);
  u16*   Hbuf   = (u16*)take((size_t)(N_TOK + 128) * FF * 2);

  hipMemsetAsync(ctl, 0, 64, stream);  // cnt+cursor zeroed (ws is re-poisoned)

  gate_k<<<8192, 256, 0, stream>>>(x, gw, gb, eid, wgt, Xb);
  count_k<<<128, 256, 0, stream>>>(eid, ctl);
  scan_k<<<1, 256, 0, stream>>>(ctl, out + (size_t)N_TOK * DD);
  pos_k<<<128, 256, 0, stream>>>(eid, wgt, ctl, sorted, wgt_s);

  transp_k<<<dim3(32, 8, EE), 256, 0, stream>>>(w1, W1t, 512, 2048);
  transp_k<<<dim3(32, 8, EE), 256, 0, stream>>>(w2, W2t, 512, 2048);
  transp_k<<<dim3(8, 32, EE), 256, 0, stream>>>(w3, W3t, 2048, 512);

  gemm1_k<<<dim3(264, 16), 256, 0, stream>>>(Xb, W1t, W2t, b1, b2, Hbuf, sorted, ctl);
  gemm2_k<<<dim3(264, 4), 256, 0, stream>>>(Hbuf, W3t, b3, sorted, wgt_s, out, ctl);
}

// Round 5
// 608.732 us; speedup vs baseline: 1.0910x; 1.0185x over previous
//
#include <hip/hip_runtime.h>
#include <hip/hip_bf16.h>

typedef unsigned short u16;
typedef __bf16 bf16x8 __attribute__((ext_vector_type(8)));
typedef float f32x4 __attribute__((ext_vector_type(4)));

#define N_TOK 32768
#define DD 512
#define FF 2048
#define EE 8

// ctl layout (ints): [0..7] cnt, [8..15] cursor, [16..24] offs, [25] ntiles,
// [32..303] tile_expert, [304..575] tile_index
#define CTL_CNT 0
#define CTL_CUR 8
#define CTL_OFF 16
#define CTL_NT 25
#define CTL_TE 32
#define CTL_TI 304

__device__ inline u16 f2bu(float f) {
  unsigned u = __builtin_bit_cast(unsigned, f);
  unsigned r = (u + 0x7fffu + ((u >> 16) & 1u)) >> 16;  // RNE
  return (u16)r;
}

__device__ inline f32x4 mfma16(bf16x8 a, bf16x8 b, f32x4 c) {
  return __builtin_amdgcn_mfma_f32_16x16x32_bf16(a, b, c, 0, 0, 0);
}

__device__ inline void gload_lds16(const void* g, void* l) {
  __builtin_amdgcn_global_load_lds(
      (const __attribute__((address_space(1))) void*)g,
      (__attribute__((address_space(3))) void*)l, 16, 0, 0);
}

// LDS tile: 128 rows x 32 cols bf16, 16B granules. Logical granule (r,g)
// lives at physical granule G' = (r*4+g) ^ (r&7)  [XOR-swizzle: fragment
// ds_read_b128 lands 2 lanes/bank = free]. global_load_lds writes linearly,
// so the WRITER inverts the swizzle on the global source address.
// Inverse of G' -> (r,g):  r = ((G'>>3)<<1) | (((G'>>2)^(G'>>4))&1),
//                          g = (G'&3) ^ (r&3).
// NOTE (R4 post-mortem): SQ_LDS_BANK_CONFLICT ~1.28e7 is the gload_lds
// WRITE side (structural 1024B/wave linear write) — don't chase it.

// ---------------- gating + bf16 convert: one wave per token ----------------
__global__ void gate_k(const float* __restrict__ x, const float* __restrict__ gw,
                       const float* __restrict__ gb, int* __restrict__ eid,
                       float* __restrict__ wgt, u16* __restrict__ Xb) {
  __shared__ float gws[DD * 9];  // padded [D][9]: 9 coprime 32 -> no conflicts
  for (int i = threadIdx.x; i < DD * EE; i += 256)
    gws[(i >> 3) * 9 + (i & 7)] = gw[i];
  __syncthreads();
  const int tok = (int)((blockIdx.x * 256 + threadIdx.x) >> 6);
  const int lane = threadIdx.x & 63;
  const float* xr = x + (size_t)tok * DD;

  // bf16 copy of this token's row (contiguous per lane)
  const float4 v0 = *(const float4*)(xr + lane * 8);
  const float4 v1 = *(const float4*)(xr + lane * 8 + 4);
  union { u16 u[8]; uint4 v; } o;
  o.u[0] = f2bu(v0.x); o.u[1] = f2bu(v0.y); o.u[2] = f2bu(v0.z); o.u[3] = f2bu(v0.w);
  o.u[4] = f2bu(v1.x); o.u[5] = f2bu(v1.y); o.u[6] = f2bu(v1.z); o.u[7] = f2bu(v1.w);
  *reinterpret_cast<uint4*>(Xb + (size_t)tok * DD + lane * 8) = o.v;

  float a[EE];
#pragma unroll
  for (int e = 0; e < EE; ++e) a[e] = 0.f;
#pragma unroll
  for (int i = 0; i < 8; ++i) {
    const int d = lane + i * 64;
    const float xv = xr[d];
#pragma unroll
    for (int e = 0; e < EE; ++e) a[e] += xv * gws[d * 9 + e];
  }
#pragma unroll
  for (int e = 0; e < EE; ++e) {
#pragma unroll
    for (int off = 32; off > 0; off >>= 1) a[e] += __shfl_xor(a[e], off);
  }
  if (lane == 0) {
    float m = -1e30f; int bi = 0;
#pragma unroll
    for (int e = 0; e < EE; ++e) {
      const float l2 = a[e] + gb[e];
      a[e] = l2;
      if (l2 > m) { m = l2; bi = e; }   // strict > : first max, matches argmax
    }
    float s = 0.f;
#pragma unroll
    for (int e = 0; e < EE; ++e) s += expf(a[e] - m);
    eid[tok] = bi;
    wgt[tok] = 1.f / s;                 // softmax prob at argmax
  }
}

// ---------------- counting sort ----------------
__global__ void count_k(const int* __restrict__ eid, int* __restrict__ ctl) {
  __shared__ int h[EE];
  if (threadIdx.x < EE) h[threadIdx.x] = 0;
  __syncthreads();
  atomicAdd(&h[eid[blockIdx.x * 256 + threadIdx.x]], 1);
  __syncthreads();
  if (threadIdx.x < EE) atomicAdd(&ctl[CTL_CNT + threadIdx.x], h[threadIdx.x]);
}

__global__ void scan_k(int* __restrict__ ctl, float* __restrict__ aux) {
  __shared__ int tstart[EE + 1];
  if (threadIdx.x == 0) {
    int o = 0, nt = 0;
    for (int e = 0; e < EE; ++e) {
      ctl[CTL_OFF + e] = o;
      ctl[CTL_CUR + e] = o;
      tstart[e] = nt;
      const int c = ctl[CTL_CNT + e];
      nt += (c + 127) >> 7;
      o += c;
    }
    tstart[EE] = nt;
    ctl[CTL_OFF + 8] = o;
    ctl[CTL_NT] = nt;
    *aux = 0.f;  // aux_loss output
  }
  __syncthreads();
  const int nt = tstart[EE];
  for (int i = threadIdx.x; i < nt; i += 256) {
    int e = 0;
    while (tstart[e + 1] <= i) ++e;
    ctl[CTL_TE + i] = e;
    ctl[CTL_TI + i] = i - tstart[e];
  }
}

__global__ void pos_k(const int* __restrict__ eid, const float* __restrict__ wgt,
                      int* __restrict__ ctl, int* __restrict__ sorted,
                      float* __restrict__ wgt_s) {
  __shared__ int h[EE], base[EE];
  const int t = blockIdx.x * 256 + threadIdx.x;
  if (threadIdx.x < EE) h[threadIdx.x] = 0;
  __syncthreads();
  const int e = eid[t];
  const int r = atomicAdd(&h[e], 1);
  __syncthreads();
  if (threadIdx.x < EE)
    base[threadIdx.x] = atomicAdd(&ctl[CTL_CUR + threadIdx.x], h[threadIdx.x]);
  __syncthreads();
  const int p = base[e] + r;
  sorted[p] = t;
  wgt_s[p] = wgt[t];
}

// out[e][c][r] = bf16(in[e][r][c]); 64x64 tiles via LDS (+2 pad: conflict-free)
__global__ void transp_k(const float* __restrict__ in, u16* __restrict__ out,
                         int R, int C) {
  __shared__ u16 tile[64][66];
  const int e = blockIdx.z;
  const int c0 = blockIdx.x * 64, r0 = blockIdx.y * 64;
  const float* ip = in + (size_t)e * R * C;
  u16* op = out + (size_t)e * R * C;
  const int tx = threadIdx.x & 63, ty = threadIdx.x >> 6;
#pragma unroll
  for (int k = 0; k < 16; ++k) {
    const int r = ty * 16 + k;
    tile[r][tx] = f2bu(ip[(size_t)(r0 + r) * C + c0 + tx]);
  }
  __syncthreads();
#pragma unroll
  for (int k = 0; k < 16; ++k) {
    const int c = ty * 16 + k;
    op[(size_t)(c0 + c) * R + r0 + tx] = tile[tx][c];
  }
}

// ---------------- GEMM1: H = gelu(Xg@W1+b1)*(Xg@W2+b2), K=512 ----------------
// 128x128 tile, 4 waves (2x2), each wave 64x64 = 4x4 frags of 16x16x32.
// 3-deep LDS pipeline with counted vmcnt (T4): never drain to 0 in the loop.
__global__ __launch_bounds__(256, 2) void gemm1_k(
    const u16* __restrict__ Xb, const u16* __restrict__ W1t,
    const u16* __restrict__ W2t, const float* __restrict__ b1,
    const float* __restrict__ b2, u16* __restrict__ Hbuf,
    const int* __restrict__ sorted, const int* __restrict__ ctl) {
  const int bx = blockIdx.x;
  if (bx >= ctl[CTL_NT]) return;
  const int e = ctl[CTL_TE + bx];
  const int ti = ctl[CTL_TI + bx];
  const int cnt = ctl[CTL_CNT + e];
  const int row0 = ctl[CTL_OFF + e] + ti * 128;
  const int rows = min(128, cnt - ti * 128);
  const int n0 = blockIdx.y * 128;

  __shared__ u16 As[3][4096];
  __shared__ u16 B1s[3][4096];
  __shared__ u16 B2s[3][4096];   // 72 KB total

  const u16* B1b = W1t + ((size_t)e * FF + n0) * DD;
  const u16* B2b = W2t + ((size_t)e * FF + n0) * DD;

  // ---- swizzled stage sources (loop-invariant per thread) ----
  const int t = threadIdx.x;
  const u16 *aSrc[2], *b1Src[2], *b2Src[2];
  int dofs[2];
#pragma unroll
  for (int s = 0; s < 2; ++s) {
    const int Gp = s * 256 + t;
    const int r = ((Gp >> 3) << 1) | (((Gp >> 2) ^ (Gp >> 4)) & 1);
    const int g = (Gp & 3) ^ (r & 3);
    dofs[s] = Gp * 8;
    const int idx = min(row0 + r, N_TOK - 1);
    aSrc[s]  = Xb + (size_t)sorted[idx] * DD + g * 8;
    b1Src[s] = B1b + (size_t)r * DD + g * 8;
    b2Src[s] = B2b + (size_t)r * DD + g * 8;
  }
  // 6 gload_lds per thread per stage
  auto stage_all = [&](int buf, int kc) {
#pragma unroll
    for (int s = 0; s < 2; ++s) gload_lds16(aSrc[s] + kc, &As[buf][dofs[s]]);
#pragma unroll
    for (int s = 0; s < 2; ++s) gload_lds16(b1Src[s] + kc, &B1s[buf][dofs[s]]);
#pragma unroll
    for (int s = 0; s < 2; ++s) gload_lds16(b2Src[s] + kc, &B2s[buf][dofs[s]]);
  };

  const f32x4 z = {0.f, 0.f, 0.f, 0.f};
  f32x4 acc1[4][4], acc2[4][4];
#pragma unroll
  for (int i = 0; i < 4; ++i)
#pragma unroll
    for (int j = 0; j < 4; ++j) { acc1[i][j] = z; acc2[i][j] = z; }

  // ---- swizzled fragment read offsets ----
  const int lane = threadIdx.x & 63;
  const int w = t >> 6;
  const int wr = w >> 1, wc = w & 1;
  const int l15 = lane & 15, g8 = (lane >> 4) * 8, xv = (lane & 7) << 3;
  int offA[4], offB[4];
#pragma unroll
  for (int i = 0; i < 4; ++i) {
    offA[i] = (((wr * 64 + i * 16 + l15) * 32 + g8) ^ xv);
    offB[i] = (((wc * 64 + i * 16 + l15) * 32 + g8) ^ xv);
  }

  stage_all(0, 0);
  stage_all(1, 32);   // 12 loads/thread in flight

  auto compute = [&](int buf) {
    bf16x8 af[4], bf1[4], bf2[4];
#pragma unroll
    for (int mi = 0; mi < 4; ++mi)
      af[mi] = *(const bf16x8*)&As[buf][offA[mi]];
#pragma unroll
    for (int ni = 0; ni < 4; ++ni) {
      bf1[ni] = *(const bf16x8*)&B1s[buf][offB[ni]];
      bf2[ni] = *(const bf16x8*)&B2s[buf][offB[ni]];
    }
    __builtin_amdgcn_s_setprio(1);
#pragma unroll
    for (int mi = 0; mi < 4; ++mi)
#pragma unroll
      for (int ni = 0; ni < 4; ++ni) {
        acc1[mi][ni] = mfma16(af[mi], bf1[ni], acc1[mi][ni]);
        acc2[mi][ni] = mfma16(af[mi], bf2[ni], acc2[mi][ni]);
      }
    __builtin_amdgcn_s_setprio(0);
  };

  // main loop: kt = 0..14; wait drains exactly stage(kt), leaves stage(kt+1)
  for (int kt = 0; kt < 15; ++kt) {
    asm volatile("s_waitcnt vmcnt(6)" ::: "memory");
    __syncthreads();  // all waves' stage(kt) landed; all prior reads done
    if (kt < 14) stage_all((kt + 2) % 3, (kt + 2) * 32);
    compute(kt % 3);
  }
  // peeled last iteration (kt = 15): only stage(15) outstanding
  asm volatile("s_waitcnt vmcnt(0)" ::: "memory");
  __syncthreads();
  compute(15 % 3);

#pragma unroll
  for (int mi = 0; mi < 4; ++mi) {
#pragma unroll
    for (int ni = 0; ni < 4; ++ni) {
      const int c = wc * 64 + ni * 16 + (lane & 15);
      const float bb1 = b1[(size_t)e * FF + n0 + c];
      const float bb2 = b2[(size_t)e * FF + n0 + c];
#pragma unroll
      for (int j = 0; j < 4; ++j) {
        const int r = wr * 64 + mi * 16 + (lane >> 4) * 4 + j;
        if (r < rows) {
          const float v1 = acc1[mi][ni][j] + bb1;
          const float v2 = acc2[mi][ni][j] + bb2;
          const float h = 0.5f * v1 * (1.f + erff(v1 * 0.70710678118f)) * v2;
          Hbuf[(size_t)(row0 + r) * FF + n0 + c] = f2bu(h);
        }
      }
    }
  }
}

// ---------------- GEMM2: out[tok] = wgt * (H@W3 + b3), K=2048 ----------------
// Same 3-deep counted-vmcnt pipeline; 4 gload_lds per thread per stage.
__global__ __launch_bounds__(256, 2) void gemm2_k(
    const u16* __restrict__ Hbuf, const u16* __restrict__ W3t,
    const float* __restrict__ b3, const int* __restrict__ sorted,
    const float* __restrict__ wgt_s, float* __restrict__ out,
    const int* __restrict__ ctl) {
  const int bx = blockIdx.x;
  if (bx >= ctl[CTL_NT]) return;
  const int e = ctl[CTL_TE + bx];
  const int ti = ctl[CTL_TI + bx];
  const int cnt = ctl[CTL_CNT + e];
  const int row0 = ctl[CTL_OFF + e] + ti * 128;
  const int rows = min(128, cnt - ti * 128);
  const int n0 = blockIdx.y * 128;

  __shared__ u16 As[3][4096];
  __shared__ u16 Bs[3][4096];   // 48 KB
  const u16* Ab = Hbuf + (size_t)row0 * FF;
  const u16* Bb = W3t + ((size_t)e * DD + n0) * FF;

  const int t = threadIdx.x;
  const u16 *aSrc[2], *bSrc[2];
  int dofs[2];
#pragma unroll
  for (int s = 0; s < 2; ++s) {
    const int Gp = s * 256 + t;
    const int r = ((Gp >> 3) << 1) | (((Gp >> 2) ^ (Gp >> 4)) & 1);
    const int g = (Gp & 3) ^ (r & 3);
    dofs[s] = Gp * 8;
    aSrc[s] = Ab + (size_t)r * FF + g * 8;
    bSrc[s] = Bb + (size_t)r * FF + g * 8;
  }
  auto stage_all = [&](int buf, int kc) {
#pragma unroll
    for (int s = 0; s < 2; ++s) gload_lds16(aSrc[s] + kc, &As[buf][dofs[s]]);
#pragma unroll
    for (int s = 0; s < 2; ++s) gload_lds16(bSrc[s] + kc, &Bs[buf][dofs[s]]);
  };

  const f32x4 z = {0.f, 0.f, 0.f, 0.f};
  f32x4 acc[4][4];
#pragma unroll
  for (int i = 0; i < 4; ++i)
#pragma unroll
    for (int j = 0; j < 4; ++j) acc[i][j] = z;

  const int lane = threadIdx.x & 63;
  const int w = t >> 6;
  const int wr = w >> 1, wc = w & 1;
  const int l15 = lane & 15, g8 = (lane >> 4) * 8, xv = (lane & 7) << 3;
  int offA[4], offB[4];
#pragma unroll
  for (int i = 0; i < 4; ++i) {
    offA[i] = (((wr * 64 + i * 16 + l15) * 32 + g8) ^ xv);
    offB[i] = (((wc * 64 + i * 16 + l15) * 32 + g8) ^ xv);
  }

  stage_all(0, 0);
  stage_all(1, 32);

  auto compute = [&](int buf) {
    bf16x8 af[4], bf[4];
#pragma unroll
    for (int mi = 0; mi < 4; ++mi)
      af[mi] = *(const bf16x8*)&As[buf][offA[mi]];
#pragma unroll
    for (int ni = 0; ni < 4; ++ni)
      bf[ni] = *(const bf16x8*)&Bs[buf][offB[ni]];
    __builtin_amdgcn_s_setprio(1);
#pragma unroll
    for (int mi = 0; mi < 4; ++mi)
#pragma unroll
      for (int ni = 0; ni < 4; ++ni)
        acc[mi][ni] = mfma16(af[mi], bf[ni], acc[mi][ni]);
    __builtin_amdgcn_s_setprio(0);
  };

  for (int kt = 0; kt < 63; ++kt) {
    asm volatile("s_waitcnt vmcnt(4)" ::: "memory");
    __syncthreads();
    if (kt < 62) stage_all((kt + 2) % 3, (kt + 2) * 32);
    compute(kt % 3);
  }
  asm volatile("s_waitcnt vmcnt(0)" ::: "memory");
  __syncthreads();
  compute(63 % 3);

#pragma unroll
  for (int mi = 0; mi < 4; ++mi) {
#pragma unroll
    for (int ni = 0; ni < 4; ++ni) {
      const int c = wc * 64 + ni * 16 + (lane & 15);
      const float bb3 = b3[(size_t)e * DD + n0 + c];
#pragma unroll
      for (int j = 0; j < 4; ++j) {
        const int r = wr * 64 + mi * 16 + (lane >> 4) * 4 + j;
        if (r < rows) {
          const int p = row0 + r;
          const int tok = sorted[p];
          out[(size_t)tok * DD + n0 + c] = wgt_s[p] * (acc[mi][ni][j] + bb3);
        }
      }
    }
  }
}

extern "C" void kernel_launch(void* const* d_in, const int* in_sizes, int n_in,
                              void* d_out, int out_size, void* d_ws, size_t ws_size,
                              hipStream_t stream) {
  const float* x  = (const float*)d_in[0];
  const float* gw = (const float*)d_in[1];
  const float* gb = (const float*)d_in[2];
  const float* w1 = (const float*)d_in[3];
  const float* b1 = (const float*)d_in[4];
  const float* w2 = (const float*)d_in[5];
  const float* b2 = (const float*)d_in[6];
  const float* w3 = (const float*)d_in[7];
  const float* b3 = (const float*)d_in[8];
  float* out = (float*)d_out;

  char* base = (char*)d_ws;
  size_t off = 0;
  auto take = [&](size_t bytes) {
    char* r = base + off;
    off += (bytes + 255) & ~(size_t)255;
    return r;
  };
  int*   ctl    = (int*)take(4096);
  int*   eid    = (int*)take((size_t)N_TOK * 4);
  float* wgt    = (float*)take((size_t)N_TOK * 4);
  int*   sorted = (int*)take((size_t)(N_TOK + 128) * 4);
  float* wgt_s  = (float*)take((size_t)(N_TOK + 128) * 4);
  u16*   Xb     = (u16*)take((size_t)N_TOK * DD * 2);
  u16*   W1t    = (u16*)take((size_t)EE * FF * DD * 2);
  u16*   W2t    = (u16*)take((size_t)EE * FF * DD * 2);
  u16*   W3t    = (u16*)take((size_t)EE * DD * FF * 2);
  u16*   Hbuf   = (u16*)take((size_t)(N_TOK + 128) * FF * 2);

  hipMemsetAsync(ctl, 0, 64, stream);  // cnt+cursor zeroed (ws is re-poisoned)

  gate_k<<<8192, 256, 0, stream>>>(x, gw, gb, eid, wgt, Xb);
  count_k<<<128, 256, 0, stream>>>(eid, ctl);
  scan_k<<<1, 256, 0, stream>>>(ctl, out + (size_t)N_TOK * DD);
  pos_k<<<128, 256, 0, stream>>>(eid, wgt, ctl, sorted, wgt_s);

  transp_k<<<dim3(32, 8, EE), 256, 0, stream>>>(w1, W1t, 512, 2048);
  transp_k<<<dim3(32, 8, EE), 256, 0, stream>>>(w2, W2t, 512, 2048);
  transp_k<<<dim3(8, 32, EE), 256, 0, stream>>>(w3, W3t, 2048, 512);

  gemm1_k<<<dim3(264, 16), 256, 0, stream>>>(Xb, W1t, W2t, b1, b2, Hbuf, sorted, ctl);
  gemm2_k<<<dim3(264, 4), 256, 0, stream>>>(Hbuf, W3t, b3, sorted, wgt_s, out, ctl);
}